// Round 1
// baseline (206.396 us; speedup 1.0000x reference)
//
#include <hip/hip_runtime.h>
#include <hip/hip_bf16.h>

#define NN 1024
#define MM 1024
#define DX 64
#define DY 16
#define HH 128

#define EPSF   1e-7f
#define LOG2E  1.4426950408889634f
#define LN2    0.6931471805599453f
#define K2     14426950.408889634f   /* LOG2E / EPS */
#define LNM    6.9314718055994531f   /* ln(1024) */

typedef __bf16          bf16x8_t __attribute__((ext_vector_type(8)));
typedef float           f32x4_t  __attribute__((ext_vector_type(4)));
typedef unsigned short  u16x8_t  __attribute__((ext_vector_type(8)));

__device__ __forceinline__ unsigned short f2bf(float f) {
    unsigned int u = __float_as_uint(f);
    u += 0x7fffu + ((u >> 16) & 1u);          // round-to-nearest-even
    return (unsigned short)(u >> 16);
}

// softplus(x) = ln(1+e^x) = ln2 * log2(1 + 2^(x*log2e)); |x| <~ 12 here, no overflow
__device__ __forceinline__ float sp(float x) {
    float t = __builtin_amdgcn_exp2f(x * LOG2E);
    return LN2 * __builtin_amdgcn_logf(1.0f + t);
}

// ---------------- prep: hx(+b1), hu, W2^T -> bf16, costT[m][n] ----------------
__global__ void prep(const float* __restrict__ X, const float* __restrict__ U,
                     const float* __restrict__ Y, const float* __restrict__ W1,
                     const float* __restrict__ b1, const float* __restrict__ W2,
                     float* __restrict__ hx, float* __restrict__ hu,
                     unsigned short* __restrict__ w2t, float* __restrict__ costT)
{
    const int blk = blockIdx.x, tid = threadIdx.x;   // 128 threads
    if (blk < NN) {
        const int n = blk, h = tid;
        float acc = b1[h];
        #pragma unroll 8
        for (int d = 0; d < DX; ++d) acc += X[n*DX+d] * W1[d*HH+h];
        hx[n*HH+h] = acc;
    } else if (blk < NN+MM) {
        const int m = blk - NN, h = tid;
        float acc = 0.f;
        #pragma unroll
        for (int d = 0; d < DY; ++d) acc += U[m*DY+d] * W1[(DX+d)*HH+h];
        hu[m*HH+h] = acc;
    } else if (blk < NN+MM+HH) {
        const int c = blk - (NN+MM), k = tid;        // w2t[c][k] = W2[k][c]
        w2t[c*HH+k] = f2bf(W2[k*HH+c]);
    } else {
        const int m = blk - (NN+MM+HH);
        float u[DY];
        #pragma unroll
        for (int d = 0; d < DY; ++d) u[d] = U[m*DY+d];
        #pragma unroll
        for (int r = 0; r < NN/128; ++r) {
            const int n = tid + r*128;
            float acc = 0.f;
            #pragma unroll
            for (int d = 0; d < DY; ++d) acc += Y[n*DY+d] * u[d];
            costT[m*NN+n] = acc;                     // costT[m][n] = Y[n]·U[m]
        }
    }
}

// ---------------- main fused kernel ----------------
// 512 blocks x 256 threads (4 waves). Block owns n in {nb, nb+1}; loops 16
// chunks of 64 m. Pairs ordered p = j*2 + i within a chunk; wave w handles
// M-tiles T = 2w, 2w+1 (16 pairs each). GEMM: A[pair, k]=softplus(hx+hu),
// B = W2 (k x hout), 16x16x32 bf16 MFMA, 8 hout-tiles, 4 k-steps.
__global__ __launch_bounds__(256, 2) void
otmain(const float* __restrict__ hx, const float* __restrict__ hu,
       const unsigned short* __restrict__ w2t,
       const float* __restrict__ b2, const float* __restrict__ W3,
       const float* __restrict__ b3, const float* __restrict__ costT,
       float* __restrict__ out)
{
    __shared__ unsigned short w2s[HH*HH];    // 32 KB, XOR-swizzled bf16 W2^T
    __shared__ float red[4][2][2];

    const int tid  = threadIdx.x;
    const int lane = tid & 63;
    const int w    = tid >> 6;
    const int nb   = blockIdx.x * 2;

    // stage W2^T into LDS; swizzle byte ^= ((row&7)<<4) to kill the 256B-stride
    // 16-way bank conflict on ds_read_b128
    #pragma unroll
    for (int it = 0; it < 8; ++it) {
        const int chunk = tid + it*256;
        const int lin   = chunk << 4;
        const int c     = lin >> 8;
        const int swz   = lin ^ ((c & 7) << 4);
        *reinterpret_cast<u16x8_t*>(reinterpret_cast<char*>(w2s) + swz) =
            *reinterpret_cast<const u16x8_t*>(reinterpret_cast<const char*>(w2t) + lin);
    }

    const int il = lane & 1;           // n-local index for A rows (pair&1)
    const int jl = (lane >> 1) & 7;    // j-within-tile for A rows (pair>>1)
    const int g  = lane >> 4;          // k-group (A/B) and row-group (C)
    const int cl = lane & 15;          // col (B/C)

    // hoist this lane's hx slice (iteration-invariant): hx[nb+il, ks*32+g*8+jj]
    float hxv[4][8];
    #pragma unroll
    for (int ks = 0; ks < 4; ++ks) {
        const float4 p0 = *reinterpret_cast<const float4*>(&hx[(nb+il)*HH + ks*32 + g*8]);
        const float4 p1 = *reinterpret_cast<const float4*>(&hx[(nb+il)*HH + ks*32 + g*8 + 4]);
        hxv[ks][0]=p0.x; hxv[ks][1]=p0.y; hxv[ks][2]=p0.z; hxv[ks][3]=p0.w;
        hxv[ks][4]=p1.x; hxv[ks][5]=p1.y; hxv[ks][6]=p1.z; hxv[ks][7]=p1.w;
    }
    float b2v[8], w3v[8];
    #pragma unroll
    for (int nt = 0; nt < 8; ++nt) { b2v[nt] = b2[nt*16+cl]; w3v[nt] = W3[nt*16+cl]; }
    const float b3v = b3[0];

    float mx[4], sv[4];
    #pragma unroll
    for (int q = 0; q < 4; ++q) { mx[q] = -3.0e38f; sv[q] = 0.f; }

    __syncthreads();

    for (int cch = 0; cch < 16; ++cch) {
        const int mb = cch * 64;
        const int m0 = mb + 16*w + jl;   // A-row m for tile T=2w
        const int m1 = m0 + 8;           // for tile T=2w+1
        f32x4_t acc0[8], acc1[8];
        #pragma unroll
        for (int nt = 0; nt < 8; ++nt)
            #pragma unroll
            for (int q = 0; q < 4; ++q) { acc0[nt][q] = 0.f; acc1[nt][q] = 0.f; }

        #pragma unroll
        for (int ks = 0; ks < 4; ++ks) {
            const int kf = ks*32 + g*8;
            const float4 u0a = *reinterpret_cast<const float4*>(&hu[m0*HH + kf]);
            const float4 u0b = *reinterpret_cast<const float4*>(&hu[m0*HH + kf + 4]);
            const float4 u1a = *reinterpret_cast<const float4*>(&hu[m1*HH + kf]);
            const float4 u1b = *reinterpret_cast<const float4*>(&hu[m1*HH + kf + 4]);
            u16x8_t a0u, a1u;
            a0u[0]=f2bf(sp(hxv[ks][0]+u0a.x)); a0u[1]=f2bf(sp(hxv[ks][1]+u0a.y));
            a0u[2]=f2bf(sp(hxv[ks][2]+u0a.z)); a0u[3]=f2bf(sp(hxv[ks][3]+u0a.w));
            a0u[4]=f2bf(sp(hxv[ks][4]+u0b.x)); a0u[5]=f2bf(sp(hxv[ks][5]+u0b.y));
            a0u[6]=f2bf(sp(hxv[ks][6]+u0b.z)); a0u[7]=f2bf(sp(hxv[ks][7]+u0b.w));
            a1u[0]=f2bf(sp(hxv[ks][0]+u1a.x)); a1u[1]=f2bf(sp(hxv[ks][1]+u1a.y));
            a1u[2]=f2bf(sp(hxv[ks][2]+u1a.z)); a1u[3]=f2bf(sp(hxv[ks][3]+u1a.w));
            a1u[4]=f2bf(sp(hxv[ks][4]+u1b.x)); a1u[5]=f2bf(sp(hxv[ks][5]+u1b.y));
            a1u[6]=f2bf(sp(hxv[ks][6]+u1b.z)); a1u[7]=f2bf(sp(hxv[ks][7]+u1b.w));
            const bf16x8_t a0 = __builtin_bit_cast(bf16x8_t, a0u);
            const bf16x8_t a1 = __builtin_bit_cast(bf16x8_t, a1u);

            #pragma unroll
            for (int nt = 0; nt < 8; ++nt) {
                const int cidx = nt*16 + cl;
                const int off  = (cidx*256 + ks*64 + g*16) ^ ((cidx & 7) << 4);
                const bf16x8_t bfr = *reinterpret_cast<const bf16x8_t*>(
                        reinterpret_cast<const char*>(w2s) + off);
                acc0[nt] = __builtin_amdgcn_mfma_f32_16x16x32_bf16(a0, bfr, acc0[nt], 0, 0, 0);
                acc1[nt] = __builtin_amdgcn_mfma_f32_16x16x32_bf16(a1, bfr, acc1[nt], 0, 0, 0);
            }
        }

        // epilogue per M-tile: layer2 softplus + W3 dot -> phi, then online LSE
        #pragma unroll
        for (int t = 0; t < 2; ++t) {
            float phi0=0.f, phi1=0.f, phi2=0.f, phi3=0.f;
            #pragma unroll
            for (int nt = 0; nt < 8; ++nt) {
                const f32x4_t a = t ? acc1[nt] : acc0[nt];
                phi0 += sp(a[0] + b2v[nt]) * w3v[nt];
                phi1 += sp(a[1] + b2v[nt]) * w3v[nt];
                phi2 += sp(a[2] + b2v[nt]) * w3v[nt];
                phi3 += sp(a[3] + b2v[nt]) * w3v[nt];
            }
            #pragma unroll
            for (int st = 1; st < 16; st <<= 1) {
                phi0 += __shfl_xor(phi0, st, 64);
                phi1 += __shfl_xor(phi1, st, 64);
                phi2 += __shfl_xor(phi2, st, 64);
                phi3 += __shfl_xor(phi3, st, 64);
            }
            // C rows r = 4g+q -> pair p = 16T + r: i = q&1 (n), j = 8T+2g+(q>>1)
            const int jm = mb + 16*w + 8*t + 2*g;
            const float2 cA = *reinterpret_cast<const float2*>(&costT[jm*NN + nb]);
            const float2 cB = *reinterpret_cast<const float2*>(&costT[(jm+1)*NN + nb]);
            const float dv0 = cA.x - (phi0 + b3v);
            const float dv1 = cA.y - (phi1 + b3v);
            const float dv2 = cB.x - (phi2 + b3v);
            const float dv3 = cB.y - (phi3 + b3v);
            #define UPD(q, d) { const float mo = mx[q]; const float mn = fmaxf(mo, (d)); \
                sv[q] = sv[q]*__builtin_amdgcn_exp2f(K2*(mo-mn)) \
                      + __builtin_amdgcn_exp2f(K2*((d)-mn)); mx[q] = mn; }
            UPD(0, dv0) UPD(1, dv1) UPD(2, dv2) UPD(3, dv3)
            #undef UPD
        }
    }

    // fold q and q+2 (same n, disjoint m-subsets) into 2 channels
    float fmx[2], fs[2];
    #pragma unroll
    for (int i = 0; i < 2; ++i) {
        const float m1v = mx[i], m2v = mx[i+2];
        const float Mv  = fmaxf(m1v, m2v);
        fmx[i] = Mv;
        fs[i]  = sv[i]  *__builtin_amdgcn_exp2f(K2*(m1v-Mv))
               + sv[i+2]*__builtin_amdgcn_exp2f(K2*(m2v-Mv));
    }
    // lanes within a 16-lane cl-group are exact duplicates: count s once
    if (cl != 0) { fs[0] = 0.f; fs[1] = 0.f; }
    #pragma unroll
    for (int st = 1; st < 64; st <<= 1) {
        #pragma unroll
        for (int i = 0; i < 2; ++i) {
            const float om = __shfl_xor(fmx[i], st, 64);
            const float os = __shfl_xor(fs[i],  st, 64);
            const float Mv = fmaxf(fmx[i], om);
            fs[i]  = fs[i]*__builtin_amdgcn_exp2f(K2*(fmx[i]-Mv))
                   + os  *__builtin_amdgcn_exp2f(K2*(om-Mv));
            fmx[i] = Mv;
        }
    }
    if (lane == 0) {
        red[w][0][0] = fmx[0]; red[w][0][1] = fs[0];
        red[w][1][0] = fmx[1]; red[w][1][1] = fs[1];
    }
    __syncthreads();
    if (tid < 2) {
        float Mv = red[0][tid][0], Sv = red[0][tid][1];
        #pragma unroll
        for (int ww = 1; ww < 4; ++ww) {
            const float om = red[ww][tid][0], os = red[ww][tid][1];
            const float M2 = fmaxf(Mv, om);
            Sv = Sv*__builtin_amdgcn_exp2f(K2*(Mv-M2))
               + os*__builtin_amdgcn_exp2f(K2*(om-M2));
            Mv = M2;
        }
        out[nb + tid] = Mv + EPSF*(LN2*__builtin_amdgcn_logf(Sv) - LNM);
    }
}

extern "C" void kernel_launch(void* const* d_in, const int* in_sizes, int n_in,
                              void* d_out, int out_size, void* d_ws, size_t ws_size,
                              hipStream_t stream)
{
    const float* X  = (const float*)d_in[0];
    const float* U  = (const float*)d_in[1];
    const float* Y  = (const float*)d_in[2];
    const float* W1 = (const float*)d_in[3];
    const float* b1 = (const float*)d_in[4];
    const float* W2 = (const float*)d_in[5];
    const float* b2 = (const float*)d_in[6];
    const float* W3 = (const float*)d_in[7];
    const float* b3 = (const float*)d_in[8];
    float* out = (float*)d_out;

    char* ws = (char*)d_ws;
    float*          hx    = (float*)(ws);                    // 512 KB
    float*          hu    = (float*)(ws + 524288);           // 512 KB
    unsigned short* w2t   = (unsigned short*)(ws + 1048576); // 32 KB
    float*          costT = (float*)(ws + 1081344);          // 4 MB

    prep<<<dim3(3200), dim3(128), 0, stream>>>(X, U, Y, W1, b1, W2, hx, hu, w2t, costT);
    otmain<<<dim3(512), dim3(256), 0, stream>>>(hx, hu, w2t, b2, W3, b3, costT, out);
}